// Round 4
// baseline (371.422 us; speedup 1.0000x reference)
//
#include <hip/hip_runtime.h>
#include <hip/hip_fp16.h>

#define IN_DIM 128
#define OUT_DIM 64
#define EPB 2048         // edges per block in k_hist/k_fill (512 thr x 4)

typedef __attribute__((ext_vector_type(8))) _Float16 half8;
typedef __attribute__((ext_vector_type(4))) float f32x4;

// Phase 1 (MFMA): wh = h @ w_w + w_b (stored fp16); s_row = wh@a1; s_col = wh@a2.
// D[c][n] = sum_k w[k][c] * h[n][k] via v_mfma_f32_16x16x32_f16.
// A = w^T (M=64 -> 4 m-tiles), B = h^T (N=16 nodes/tile), K=128 -> 4 k-tiles.
// Also zeroes nodecnt[] (grid covers n_nodes) so the launch sequence is
// idempotent under graph replay without a memset.
__global__ __launch_bounds__(256) void k_wh(
    const float* __restrict__ h, const float* __restrict__ w_w,
    const float* __restrict__ w_b, const float* __restrict__ a_w,
    __half* __restrict__ wh, float* __restrict__ s_row,
    float* __restrict__ s_col, int* __restrict__ nodecnt, int n_nodes) {
  {
    int tid = blockIdx.x * 256 + threadIdx.x;
    if (tid < n_nodes) nodecnt[tid] = 0;
  }
  __shared__ _Float16 wf[4 * 4 * 64 * 8];
  for (int idx = threadIdx.x; idx < IN_DIM * OUT_DIM; idx += 256) {
    int k = idx >> 6, c = idx & 63;            // w_w[k][c], coalesced read
    int mt = c >> 4;
    int kt = k >> 5;
    int l = (((k >> 3) & 3) << 4) | (c & 15);  // lane that owns this (k,c)
    int j = k & 7;
    wf[(((mt << 2) | kt) << 9) | (l << 3) | j] = (_Float16)w_w[idx];
  }
  __syncthreads();

  const int lane = threadIdx.x & 63;
  const int wv = threadIdx.x >> 6;

  half8 A[4][4];
#pragma unroll
  for (int mt = 0; mt < 4; ++mt)
#pragma unroll
    for (int kt = 0; kt < 4; ++kt)
      A[mt][kt] =
          *(const half8*)&wf[(((mt << 2) | kt) << 9) | (lane << 3)];

  const int cbase = (lane >> 4) << 2;
  f32x4 bq[4], a1q[4], a2q[4];
#pragma unroll
  for (int mt = 0; mt < 4; ++mt) {
    bq[mt] = *(const f32x4*)&w_b[mt * 16 + cbase];
    a1q[mt] = *(const f32x4*)&a_w[mt * 16 + cbase];
    a2q[mt] = *(const f32x4*)&a_w[OUT_DIM + mt * 16 + cbase];
  }

  const int ntiles = (n_nodes + 15) >> 4;
  const int tstride = gridDim.x << 2;
  for (int t = blockIdx.x * 4 + wv; t < ntiles; t += tstride) {
    const int n0 = t << 4;
    const int node = n0 + (lane & 15);
    const int nodec = node < n_nodes ? node : n_nodes - 1;
    const float4* hv =
        (const float4*)(h + (size_t)nodec * IN_DIM + ((lane >> 4) << 3));
    float4 p[8];
#pragma unroll
    for (int kt = 0; kt < 4; ++kt) {
      p[2 * kt] = hv[kt * 8];
      p[2 * kt + 1] = hv[kt * 8 + 1];
    }
    f32x4 C[4];
#pragma unroll
    for (int mt = 0; mt < 4; ++mt) C[mt] = (f32x4){0.f, 0.f, 0.f, 0.f};
#pragma unroll
    for (int kt = 0; kt < 4; ++kt) {
      const float4 u = p[2 * kt], v = p[2 * kt + 1];
      half8 B;
      B[0] = (_Float16)u.x; B[1] = (_Float16)u.y;
      B[2] = (_Float16)u.z; B[3] = (_Float16)u.w;
      B[4] = (_Float16)v.x; B[5] = (_Float16)v.y;
      B[6] = (_Float16)v.z; B[7] = (_Float16)v.w;
#pragma unroll
      for (int mt = 0; mt < 4; ++mt)
        C[mt] = __builtin_amdgcn_mfma_f32_16x16x32_f16(A[mt][kt], B, C[mt],
                                                       0, 0, 0);
    }
    float sr = 0.f, sc = 0.f;
    uint2 q[4];
#pragma unroll
    for (int mt = 0; mt < 4; ++mt) {
      f32x4 d = C[mt] + bq[mt];
      sr += d[0] * a1q[mt][0] + d[1] * a1q[mt][1] + d[2] * a1q[mt][2] +
            d[3] * a1q[mt][3];
      sc += d[0] * a2q[mt][0] + d[1] * a2q[mt][1] + d[2] * a2q[mt][2] +
            d[3] * a2q[mt][3];
      __half2 lo = __floats2half2_rn(d[0], d[1]);
      __half2 hi = __floats2half2_rn(d[2], d[3]);
      q[mt].x = *(unsigned int*)&lo;
      q[mt].y = *(unsigned int*)&hi;
    }
    if (node < n_nodes) {
      uint2* wrow = (uint2*)(wh + (size_t)node * OUT_DIM + cbase);
      wrow[0] = q[0];
      wrow[4] = q[1];
      wrow[8] = q[2];
      wrow[12] = q[3];
    }
    sr += __shfl_xor(sr, 16, 64);
    sr += __shfl_xor(sr, 32, 64);
    sc += __shfl_xor(sc, 16, 64);
    sc += __shfl_xor(sc, 32, 64);
    if (lane < 16 && node < n_nodes) {
      s_row[node] = sr;
      s_col[node] = sc;
    }
  }
}

// Per-node degree histogram via device-scope atomics (fire-and-forget).
__global__ __launch_bounds__(512) void k_hist(
    const int* __restrict__ ei, int* __restrict__ nodecnt, int nedges) {
  const int e0 = blockIdx.x * EPB;
  if (e0 + EPB <= nedges) {
    const int e = e0 + threadIdx.x;
    int r0 = ei[e];
    int r1 = ei[e + 512];
    int r2 = ei[e + 1024];
    int r3 = ei[e + 1536];
    atomicAdd(&nodecnt[r0], 1);
    atomicAdd(&nodecnt[r1], 1);
    atomicAdd(&nodecnt[r2], 1);
    atomicAdd(&nodecnt[r3], 1);
  } else {
#pragma unroll
    for (int r = 0; r < EPB / 512; ++r) {
      int e = e0 + r * 512 + threadIdx.x;
      if (e < nedges) atomicAdd(&nodecnt[ei[e]], 1);
    }
  }
}

// Hierarchical exclusive scan of nodecnt -> nodeoffs (CSR starts).
// scan1: per-block (1024-wide) exclusive scan + block totals.
__global__ __launch_bounds__(1024) void k_scan1(
    const int* __restrict__ nodecnt, int* __restrict__ nodeoffs,
    int* __restrict__ blocksum, int n_nodes) {
  __shared__ int sd[1024];
  const int t = threadIdx.x;
  const int i = blockIdx.x * 1024 + t;
  int v = (i < n_nodes) ? nodecnt[i] : 0;
  sd[t] = v;
  __syncthreads();
  for (int off = 1; off < 1024; off <<= 1) {
    int x = (t >= off) ? sd[t - off] : 0;
    __syncthreads();
    sd[t] += x;
    __syncthreads();
  }
  if (i < n_nodes) nodeoffs[i] = sd[t] - v;
  if (t == 1023) blocksum[blockIdx.x] = sd[1023];
}

// scan2: single-block exclusive scan of block totals (nsb <= 128).
__global__ __launch_bounds__(128) void k_scan2(
    const int* __restrict__ blocksum, int* __restrict__ blockbase, int nsb) {
  __shared__ int sd[128];
  const int t = threadIdx.x;
  int v = (t < nsb) ? blocksum[t] : 0;
  sd[t] = v;
  __syncthreads();
  for (int off = 1; off < 128; off <<= 1) {
    int x = (t >= off) ? sd[t - off] : 0;
    __syncthreads();
    sd[t] += x;
    __syncthreads();
  }
  if (t < nsb) blockbase[t] = sd[t] - v;
}

// scan3: add block bases back -> final CSR start offsets.
__global__ __launch_bounds__(1024) void k_scan3(
    int* __restrict__ nodeoffs, const int* __restrict__ blockbase,
    int n_nodes) {
  const int i = blockIdx.x * 1024 + threadIdx.x;
  if (i < n_nodes) nodeoffs[i] += blockbase[blockIdx.x];
}

// Phase 2: score -> alpha -> DIRECT CSR scatter. pos comes from a global
// atomic cursor on nodeoffs (issued before the gathers so its latency
// overlaps the s_row/s_col wait). After this kernel nodeoffs[v] = CSR end.
// Within-node order is nondeterministic (fp32 sum-order noise only).
__global__ __launch_bounds__(512) void k_fill(
    const int* __restrict__ ei, const float* __restrict__ edge_attr,
    const float* __restrict__ a_w, const float* __restrict__ a_b,
    const float* __restrict__ s_row, const float* __restrict__ s_col,
    int* __restrict__ nodeoffs, int2* __restrict__ ent, int nedges) {
  float aw0 = a_w[128], aw1 = a_w[129], aw2 = a_w[130], aw3 = a_w[131];
  float aw4 = a_w[132], aw5 = a_w[133], aw6 = a_w[134], aw7 = a_w[135];
  float ab = a_b[0];
  const int e0 = blockIdx.x * EPB;
  if (e0 + EPB <= nedges) {
    const int e = e0 + threadIdx.x;
    int row[4], col[4];
#pragma unroll
    for (int r = 0; r < 4; ++r) {
      row[r] = ei[e + r * 512];
      col[r] = ei[nedges + e + r * 512];
    }
    int pos[4];
#pragma unroll
    for (int r = 0; r < 4; ++r) pos[r] = atomicAdd(&nodeoffs[row[r]], 1);
    float4 u[4], v[4];
#pragma unroll
    for (int r = 0; r < 4; ++r) {
      const float4* ea = (const float4*)(edge_attr + (size_t)(e + r * 512) * 8);
      u[r] = ea[0];
      v[r] = ea[1];
    }
    float sr[4], sc[4];
#pragma unroll
    for (int r = 0; r < 4; ++r) {
      sr[r] = s_row[row[r]];
      sc[r] = s_col[col[r]];
    }
#pragma unroll
    for (int r = 0; r < 4; ++r) {
      float s = sr[r] + sc[r] + ab;
      s += u[r].x * aw0 + u[r].y * aw1 + u[r].z * aw2 + u[r].w * aw3;
      s += v[r].x * aw4 + v[r].y * aw5 + v[r].z * aw6 + v[r].w * aw7;
      float ev = (s > 0.f) ? s : 0.01f * s;  // leaky_relu
      float alpha = __expf(ev);  // softmax shift-invariance: no segment max
      ent[pos[r]] = make_int2(col[r], __float_as_int(alpha));
    }
  } else {
    for (int r = 0; r < EPB / 512; ++r) {
      int e = e0 + r * 512 + threadIdx.x;
      if (e < nedges) {
        int row = ei[e];
        int col = ei[nedges + e];
        int pos = atomicAdd(&nodeoffs[row], 1);
        const float4* ea = (const float4*)(edge_attr + (size_t)e * 8);
        float4 u = ea[0], v = ea[1];
        float s = s_row[row] + s_col[col] + ab;
        s += u.x * aw0 + u.y * aw1 + u.z * aw2 + u.w * aw3;
        s += v.x * aw4 + v.y * aw5 + v.z * aw6 + v.w * aw7;
        float ev = (s > 0.f) ? s : 0.01f * s;
        float alpha = __expf(ev);
        ent[pos] = make_int2(col, __float_as_int(alpha));
      }
    }
  }
}

// Phase 3: pull aggregation, eighth-wave: 8 lanes x 16B fp16 per edge,
// 8 edges/wave in flight x2 unroll = 16 edges of MLP per iteration.
// nodeoffs[v] is the CSR END after k_fill; start = end - deg.
__global__ __launch_bounds__(256) void k_agg(
    const int* __restrict__ nodeoffs, const int* __restrict__ nodecnt,
    const int2* __restrict__ ent, const __half* __restrict__ wh,
    float* __restrict__ out, int n_nodes) {
  int v = blockIdx.x * 4 + (threadIdx.x >> 6);
  if (v >= n_nodes) return;
  const int lane = threadIdx.x & 63;
  const int slot = lane >> 3, sub = lane & 7;  // 8 slots x 8 lanes
  const int endp = __builtin_amdgcn_readfirstlane(nodeoffs[v]);
  const int deg = __builtin_amdgcn_readfirstlane(nodecnt[v]);
  const int start = endp - deg;
  const uint4* whq = (const uint4*)wh;  // 16B = 8 halves per lane
  float acc[8] = {0.f, 0.f, 0.f, 0.f, 0.f, 0.f, 0.f, 0.f};
  float l = 0.f;
  for (int base = 0; base < deg; base += 16) {
    const int i0 = base + slot, i1 = base + 8 + slot;
    const bool g0 = i0 < deg, g1 = i1 < deg;
    int2 p0 = make_int2(0, 0), p1 = make_int2(0, 0);
    if (g0) p0 = ent[start + i0];
    if (g1) p1 = ent[start + i1];
    uint4 q0 = make_uint4(0, 0, 0, 0), q1 = make_uint4(0, 0, 0, 0);
    if (g0) q0 = whq[(size_t)p0.x * 8 + sub];
    if (g1) q1 = whq[(size_t)p1.x * 8 + sub];
    if (g0) {
      float a = __int_as_float(p0.y);
      float2 f0 = __half22float2(*(__half2*)&q0.x);
      float2 f1 = __half22float2(*(__half2*)&q0.y);
      float2 f2 = __half22float2(*(__half2*)&q0.z);
      float2 f3 = __half22float2(*(__half2*)&q0.w);
      acc[0] = fmaf(a, f0.x, acc[0]); acc[1] = fmaf(a, f0.y, acc[1]);
      acc[2] = fmaf(a, f1.x, acc[2]); acc[3] = fmaf(a, f1.y, acc[3]);
      acc[4] = fmaf(a, f2.x, acc[4]); acc[5] = fmaf(a, f2.y, acc[5]);
      acc[6] = fmaf(a, f3.x, acc[6]); acc[7] = fmaf(a, f3.y, acc[7]);
      if (sub == 0) l += a;
    }
    if (g1) {
      float a = __int_as_float(p1.y);
      float2 f0 = __half22float2(*(__half2*)&q1.x);
      float2 f1 = __half22float2(*(__half2*)&q1.y);
      float2 f2 = __half22float2(*(__half2*)&q1.z);
      float2 f3 = __half22float2(*(__half2*)&q1.w);
      acc[0] = fmaf(a, f0.x, acc[0]); acc[1] = fmaf(a, f0.y, acc[1]);
      acc[2] = fmaf(a, f1.x, acc[2]); acc[3] = fmaf(a, f1.y, acc[3]);
      acc[4] = fmaf(a, f2.x, acc[4]); acc[5] = fmaf(a, f2.y, acc[5]);
      acc[6] = fmaf(a, f3.x, acc[6]); acc[7] = fmaf(a, f3.y, acc[7]);
      if (sub == 0) l += a;
    }
  }
  // reduce across the 8 slot-groups (stride 8)
#pragma unroll
  for (int c = 0; c < 8; ++c) {
    acc[c] += __shfl_xor(acc[c], 8, 64);
    acc[c] += __shfl_xor(acc[c], 16, 64);
    acc[c] += __shfl_xor(acc[c], 32, 64);
  }
  l += __shfl_xor(l, 8, 64);
  l += __shfl_xor(l, 16, 64);
  l += __shfl_xor(l, 32, 64);
  float lt = __shfl(l, 0, 64);
  if (slot == 0) {
    float inv = 1.0f / (lt + 1e-8f);
    float4 o0 = make_float4(acc[0] * inv, acc[1] * inv, acc[2] * inv,
                            acc[3] * inv);
    float4 o1 = make_float4(acc[4] * inv, acc[5] * inv, acc[6] * inv,
                            acc[7] * inv);
    float4* orow = (float4*)out + (size_t)v * 16 + sub * 2;
    orow[0] = o0;
    orow[1] = o1;
  }
}

extern "C" void kernel_launch(void* const* d_in, const int* in_sizes, int n_in,
                              void* d_out, int out_size, void* d_ws, size_t ws_size,
                              hipStream_t stream) {
  const float* h         = (const float*)d_in[0];
  const int*   ei        = (const int*)d_in[1];
  const float* edge_attr = (const float*)d_in[2];
  const float* w_w       = (const float*)d_in[3];
  const float* w_b       = (const float*)d_in[4];
  const float* a_w       = (const float*)d_in[5];
  const float* a_b       = (const float*)d_in[6];
  const int n_nodes = in_sizes[0] / IN_DIM;
  const int nedges  = in_sizes[1] / 2;
  const int nebl = (nedges + EPB - 1) / EPB;        // ~782
  const int nsb  = (n_nodes + 1023) / 1024;         // ~98 (<=128)

  // Workspace (~27.5 MB):
  __half* wh       = (__half*)d_ws;                           // n*64 fp16
  int2*  ent       = (int2*)(wh + (size_t)n_nodes * OUT_DIM); // nedges
  int*   nodecnt   = (int*)(ent + (size_t)nedges);            // n
  int*   nodeoffs  = nodecnt + n_nodes;                       // n
  int*   blocksum  = nodeoffs + n_nodes;                      // 128
  int*   blockbase = blocksum + 128;                          // 128
  float* s_row     = (float*)(blockbase + 128);               // n
  float* s_col     = s_row + n_nodes;                         // n

  k_wh<<<640, 256, 0, stream>>>(h, w_w, w_b, a_w, wh, s_row, s_col,
                                nodecnt, n_nodes);
  k_hist<<<nebl, 512, 0, stream>>>(ei, nodecnt, nedges);
  k_scan1<<<nsb, 1024, 0, stream>>>(nodecnt, nodeoffs, blocksum, n_nodes);
  k_scan2<<<1, 128, 0, stream>>>(blocksum, blockbase, nsb);
  k_scan3<<<nsb, 1024, 0, stream>>>(nodeoffs, blockbase, n_nodes);
  k_fill<<<nebl, 512, 0, stream>>>(ei, edge_attr, a_w, a_b, s_row, s_col,
                                   nodeoffs, ent, nedges);
  k_agg<<<(n_nodes + 3) / 4, 256, 0, stream>>>(nodeoffs, nodecnt, ent, wh,
                                               (float*)d_out, n_nodes);
}

// Round 5
// 258.263 us; speedup vs baseline: 1.4382x; 1.4382x over previous
//
#include <hip/hip_runtime.h>
#include <hip/hip_fp16.h>

#define IN_DIM 128
#define OUT_DIM 64
#define RPB 512          // rows per bucket
#define MAXB 200         // max buckets  (n_nodes <= 102400)
#define EPB 2048         // edges per block in k_pre/k_fill (512 thr x 4)

typedef __attribute__((ext_vector_type(8))) _Float16 half8;
typedef __attribute__((ext_vector_type(4))) float f32x4;

// Phase 1 (MFMA): wh = h @ w_w + w_b (stored fp16); s_row = wh@a1.
// s_col is NOT precomputed: k_agg recomputes wh@a2 from the gathered fp16
// wh row (score completion moved into the aggregation).
__global__ __launch_bounds__(256) void k_wh(
    const float* __restrict__ h, const float* __restrict__ w_w,
    const float* __restrict__ w_b, const float* __restrict__ a_w,
    __half* __restrict__ wh, float* __restrict__ s_row, int n_nodes) {
  __shared__ _Float16 wf[4 * 4 * 64 * 8];
  for (int idx = threadIdx.x; idx < IN_DIM * OUT_DIM; idx += 256) {
    int k = idx >> 6, c = idx & 63;            // w_w[k][c], coalesced read
    int mt = c >> 4;
    int kt = k >> 5;
    int l = (((k >> 3) & 3) << 4) | (c & 15);  // lane that owns this (k,c)
    int j = k & 7;
    wf[(((mt << 2) | kt) << 9) | (l << 3) | j] = (_Float16)w_w[idx];
  }
  __syncthreads();

  const int lane = threadIdx.x & 63;
  const int wv = threadIdx.x >> 6;

  half8 A[4][4];
#pragma unroll
  for (int mt = 0; mt < 4; ++mt)
#pragma unroll
    for (int kt = 0; kt < 4; ++kt)
      A[mt][kt] =
          *(const half8*)&wf[(((mt << 2) | kt) << 9) | (lane << 3)];

  const int cbase = (lane >> 4) << 2;
  f32x4 bq[4], a1q[4];
#pragma unroll
  for (int mt = 0; mt < 4; ++mt) {
    bq[mt] = *(const f32x4*)&w_b[mt * 16 + cbase];
    a1q[mt] = *(const f32x4*)&a_w[mt * 16 + cbase];
  }

  const int ntiles = (n_nodes + 15) >> 4;
  const int tstride = gridDim.x << 2;
  for (int t = blockIdx.x * 4 + wv; t < ntiles; t += tstride) {
    const int n0 = t << 4;
    const int node = n0 + (lane & 15);
    const int nodec = node < n_nodes ? node : n_nodes - 1;
    const float4* hv =
        (const float4*)(h + (size_t)nodec * IN_DIM + ((lane >> 4) << 3));
    float4 p[8];
#pragma unroll
    for (int kt = 0; kt < 4; ++kt) {
      p[2 * kt] = hv[kt * 8];
      p[2 * kt + 1] = hv[kt * 8 + 1];
    }
    f32x4 C[4];
#pragma unroll
    for (int mt = 0; mt < 4; ++mt) C[mt] = (f32x4){0.f, 0.f, 0.f, 0.f};
#pragma unroll
    for (int kt = 0; kt < 4; ++kt) {
      const float4 u = p[2 * kt], v = p[2 * kt + 1];
      half8 B;
      B[0] = (_Float16)u.x; B[1] = (_Float16)u.y;
      B[2] = (_Float16)u.z; B[3] = (_Float16)u.w;
      B[4] = (_Float16)v.x; B[5] = (_Float16)v.y;
      B[6] = (_Float16)v.z; B[7] = (_Float16)v.w;
#pragma unroll
      for (int mt = 0; mt < 4; ++mt)
        C[mt] = __builtin_amdgcn_mfma_f32_16x16x32_f16(A[mt][kt], B, C[mt],
                                                       0, 0, 0);
    }
    float sr = 0.f;
    uint2 q[4];
#pragma unroll
    for (int mt = 0; mt < 4; ++mt) {
      f32x4 d = C[mt] + bq[mt];
      sr += d[0] * a1q[mt][0] + d[1] * a1q[mt][1] + d[2] * a1q[mt][2] +
            d[3] * a1q[mt][3];
      __half2 lo = __floats2half2_rn(d[0], d[1]);
      __half2 hi = __floats2half2_rn(d[2], d[3]);
      q[mt].x = *(unsigned int*)&lo;
      q[mt].y = *(unsigned int*)&hi;
    }
    if (node < n_nodes) {
      uint2* wrow = (uint2*)(wh + (size_t)node * OUT_DIM + cbase);
      wrow[0] = q[0];
      wrow[4] = q[1];
      wrow[8] = q[2];
      wrow[12] = q[3];
    }
    sr += __shfl_xor(sr, 16, 64);
    sr += __shfl_xor(sr, 32, 64);
    if (lane < 16 && node < n_nodes) {
      s_row[node] = sr;
    }
  }
}

// Per-block bucket histogram. EPB=2048 -> ~782 blocks.
__global__ __launch_bounds__(512) void k_pre(
    const int* __restrict__ ei, int* __restrict__ blockhist, int nedges) {
  __shared__ int hist[MAXB];
  for (int b = threadIdx.x; b < MAXB; b += 512) hist[b] = 0;
  __syncthreads();
  const int e0 = blockIdx.x * EPB;
  if (e0 + EPB <= nedges) {
    const int e = e0 + threadIdx.x;
    int r0 = ei[e];
    int r1 = ei[e + 512];
    int r2 = ei[e + 1024];
    int r3 = ei[e + 1536];
    atomicAdd(&hist[r0 >> 9], 1);
    atomicAdd(&hist[r1 >> 9], 1);
    atomicAdd(&hist[r2 >> 9], 1);
    atomicAdd(&hist[r3 >> 9], 1);
  } else {
#pragma unroll
    for (int r = 0; r < EPB / 512; ++r) {
      int e = e0 + r * 512 + threadIdx.x;
      if (e < nedges) atomicAdd(&hist[ei[e] >> 9], 1);
    }
  }
  __syncthreads();
  for (int b = threadIdx.x; b < MAXB; b += 512)
    blockhist[blockIdx.x * MAXB + b] = hist[b];
}

// Per-bucket exclusive scan over up to 1024 blocks of LINE-PADDED counts
// (roundup 8 entries = 64B): every (block,bucket) run starts line-aligned.
__global__ __launch_bounds__(512) void k_scanA(
    const int* __restrict__ blockhist, int* __restrict__ boff,
    int* __restrict__ cnt, int nbl) {
  __shared__ int sd[512];
  const int b = blockIdx.x, t = threadIdx.x;
  int i0 = 2 * t, i1 = 2 * t + 1;
  int v0 = (i0 < nbl) ? ((blockhist[i0 * MAXB + b] + 7) & ~7) : 0;
  int v1 = (i1 < nbl) ? ((blockhist[i1 * MAXB + b] + 7) & ~7) : 0;
  int ts = v0 + v1;
  sd[t] = ts;
  __syncthreads();
  for (int off = 1; off < 512; off <<= 1) {
    int x = (t >= off) ? sd[t - off] : 0;
    __syncthreads();
    sd[t] += x;
    __syncthreads();
  }
  int excl = sd[t] - ts;
  if (i0 < nbl) boff[i0 * MAXB + b] = excl;
  if (i1 < nbl) boff[i1 * MAXB + b] = excl + v0;
  if (t == 511) cnt[b] = sd[511];  // padded bucket total (multiple of 8)
}

// Exclusive scan of 128B-padded bucket counts -> bucket bases.
__global__ __launch_bounds__(256) void k_scanB(
    const int* __restrict__ cnt, int* __restrict__ bbase, int nb) {
  __shared__ int sd[256];
  int t = threadIdx.x;
  int pc = (t < nb) ? ((cnt[t] + 15) & ~15) : 0;
  sd[t] = pc;
  __syncthreads();
  for (int off = 1; off < 256; off <<= 1) {
    int x = (t >= off) ? sd[t - off] : 0;
    __syncthreads();
    sd[t] += x;
    __syncthreads();
  }
  if (t < nb) bbase[t] = sd[t] - pc;
}

// Phase 2: NO random gathers. Pure coalesced streams (ei, edge_attr) ->
// ea3 = edge_attr@a3 -> deterministic line-aligned bucket-grouped scatter.
// Entry payload = ea3 (score completed in k_agg). Tails padded with x=-1.
__global__ __launch_bounds__(512) void k_fill(
    const int* __restrict__ ei, const float* __restrict__ edge_attr,
    const float* __restrict__ a_w,
    const int* __restrict__ boff, const int* __restrict__ bbase,
    int2* __restrict__ entA, int nedges, int nb) {
  __shared__ int cur[MAXB];
  for (int b = threadIdx.x; b < MAXB; b += 512)
    cur[b] = (b < nb) ? bbase[b] + boff[blockIdx.x * MAXB + b] : 0;
  float aw0 = a_w[128], aw1 = a_w[129], aw2 = a_w[130], aw3 = a_w[131];
  float aw4 = a_w[132], aw5 = a_w[133], aw6 = a_w[134], aw7 = a_w[135];
  __syncthreads();
  const int e0 = blockIdx.x * EPB;
  if (e0 + EPB <= nedges) {
    const int e = e0 + threadIdx.x;
    int row[4], col[4];
#pragma unroll
    for (int r = 0; r < 4; ++r) {
      row[r] = ei[e + r * 512];
      col[r] = ei[nedges + e + r * 512];
    }
    float4 u[4], v[4];
#pragma unroll
    for (int r = 0; r < 4; ++r) {
      const float4* ea = (const float4*)(edge_attr + (size_t)(e + r * 512) * 8);
      u[r] = ea[0];
      v[r] = ea[1];
    }
#pragma unroll
    for (int r = 0; r < 4; ++r) {
      float s = u[r].x * aw0 + u[r].y * aw1 + u[r].z * aw2 + u[r].w * aw3;
      s += v[r].x * aw4 + v[r].y * aw5 + v[r].z * aw6 + v[r].w * aw7;
      int pos = atomicAdd(&cur[row[r] >> 9], 1);
      entA[pos] =
          make_int2(((row[r] & 511) << 17) | col[r], __float_as_int(s));
    }
  } else {
    for (int r = 0; r < EPB / 512; ++r) {
      int e = e0 + r * 512 + threadIdx.x;
      if (e < nedges) {
        int row = ei[e];
        int col = ei[nedges + e];
        const float4* ea = (const float4*)(edge_attr + (size_t)e * 8);
        float4 u = ea[0], v = ea[1];
        float s = u.x * aw0 + u.y * aw1 + u.z * aw2 + u.w * aw3;
        s += v.x * aw4 + v.y * aw5 + v.z * aw6 + v.w * aw7;
        int pos = atomicAdd(&cur[row >> 9], 1);
        entA[pos] = make_int2(((row & 511) << 17) | col, __float_as_int(s));
      }
    }
  }
  __syncthreads();
  // pad each run's tail to its 64B line end with sentinels
  for (int b = threadIdx.x; b < nb; b += 512) {
    int c = cur[b], end = (c + 7) & ~7;
    for (int k = c; k < end; ++k) entA[k] = make_int2(-1, 0);
  }
}

// Per-bucket counting sort (hist in LDS, entries in global). Skips
// sentinels. Emits node CSR offsets/counts + row-sorted packed entries.
__global__ __launch_bounds__(512) void k_sortb(
    const int2* __restrict__ entA, int2* __restrict__ entB,
    const int* __restrict__ cnt, const int* __restrict__ bbase,
    int* __restrict__ nodeoffs, int* __restrict__ nodecnt, int n_nodes) {
  __shared__ int hist[RPB];
  __shared__ int loffs[RPB];
  __shared__ int cur[RPB];
  const int b = blockIdx.x, t = threadIdx.x;
  const int c = cnt[b];       // padded count
  const int base = bbase[b];
  const int row0 = b << 9;
  hist[t] = 0;
  __syncthreads();
  for (int i = t; i < c; i += 512) {
    int x = entA[base + i].x;
    if (x >= 0) atomicAdd(&hist[x >> 17], 1);
  }
  __syncthreads();
  int hh = hist[t];
  loffs[t] = hh;
  __syncthreads();
  for (int off = 1; off < 512; off <<= 1) {
    int x = (t >= off) ? loffs[t - off] : 0;
    __syncthreads();
    loffs[t] += x;
    __syncthreads();
  }
  int excl = loffs[t] - hh;
  cur[t] = excl;
  int node = row0 + t;
  if (node < n_nodes) {
    nodeoffs[node] = base + excl;  // entB packed per bucket at padded base
    nodecnt[node] = hh;
  }
  __syncthreads();
  for (int i = t; i < c; i += 512) {
    int2 p = entA[base + i];
    if (p.x >= 0) {
      int pos = atomicAdd(&cur[p.x >> 17], 1);
      entB[base + pos] = p;
    }
  }
}

// Phase 3: pull aggregation + on-the-fly score finish.
// 8 lanes x 16B fp16 per edge, 16 edges of MLP per iteration.
// Per edge: s = s_row[v] + dot(whrow, a2) + ea3 + ab ; alpha = exp(leaky(s)).
// dot(whrow, a2) reduced across the 8-lane sub-group (shfl_xor 1/2/4).
__global__ __launch_bounds__(256) void k_agg(
    const int* __restrict__ nodeoffs, const int* __restrict__ nodecnt,
    const int2* __restrict__ ent, const __half* __restrict__ wh,
    const float* __restrict__ s_row, const float* __restrict__ a_w,
    const float* __restrict__ a_b, float* __restrict__ out, int n_nodes) {
  int v = blockIdx.x * 4 + (threadIdx.x >> 6);
  if (v >= n_nodes) return;
  const int lane = threadIdx.x & 63;
  const int slot = lane >> 3, sub = lane & 7;  // 8 slots x 8 lanes
  const int start = __builtin_amdgcn_readfirstlane(nodeoffs[v]);
  const int deg = __builtin_amdgcn_readfirstlane(nodecnt[v]);
  const float sab = s_row[v] + a_b[0];  // wave-uniform
  // a2 slice for this lane's 8 wh dims
  const float4* a2p = (const float4*)(a_w + OUT_DIM + sub * 8);
  const float4 a2lo = a2p[0], a2hi = a2p[1];
  const uint4* whq = (const uint4*)wh;  // 16B = 8 halves per lane
  float acc[8] = {0.f, 0.f, 0.f, 0.f, 0.f, 0.f, 0.f, 0.f};
  float l = 0.f;
  for (int base = 0; base < deg; base += 16) {
    const int i0 = base + slot, i1 = base + 8 + slot;
    const bool g0 = i0 < deg, g1 = i1 < deg;
    int2 p0 = make_int2(0, 0), p1 = make_int2(0, 0);
    if (g0) p0 = ent[start + i0];
    if (g1) p1 = ent[start + i1];
    uint4 q0 = make_uint4(0, 0, 0, 0), q1 = make_uint4(0, 0, 0, 0);
    if (g0) q0 = whq[(size_t)(p0.x & 0x1FFFF) * 8 + sub];
    if (g1) q1 = whq[(size_t)(p1.x & 0x1FFFF) * 8 + sub];
    if (g0) {
      float2 f0 = __half22float2(*(__half2*)&q0.x);
      float2 f1 = __half22float2(*(__half2*)&q0.y);
      float2 f2 = __half22float2(*(__half2*)&q0.z);
      float2 f3 = __half22float2(*(__half2*)&q0.w);
      float d = f0.x * a2lo.x + f0.y * a2lo.y + f1.x * a2lo.z +
                f1.y * a2lo.w + f2.x * a2hi.x + f2.y * a2hi.y +
                f3.x * a2hi.z + f3.y * a2hi.w;
      d += __shfl_xor(d, 1, 64);
      d += __shfl_xor(d, 2, 64);
      d += __shfl_xor(d, 4, 64);
      float s = sab + __int_as_float(p0.y) + d;
      float ev = (s > 0.f) ? s : 0.01f * s;  // leaky_relu
      float a = __expf(ev);
      acc[0] = fmaf(a, f0.x, acc[0]); acc[1] = fmaf(a, f0.y, acc[1]);
      acc[2] = fmaf(a, f1.x, acc[2]); acc[3] = fmaf(a, f1.y, acc[3]);
      acc[4] = fmaf(a, f2.x, acc[4]); acc[5] = fmaf(a, f2.y, acc[5]);
      acc[6] = fmaf(a, f3.x, acc[6]); acc[7] = fmaf(a, f3.y, acc[7]);
      if (sub == 0) l += a;
    }
    if (g1) {
      float2 f0 = __half22float2(*(__half2*)&q1.x);
      float2 f1 = __half22float2(*(__half2*)&q1.y);
      float2 f2 = __half22float2(*(__half2*)&q1.z);
      float2 f3 = __half22float2(*(__half2*)&q1.w);
      float d = f0.x * a2lo.x + f0.y * a2lo.y + f1.x * a2lo.z +
                f1.y * a2lo.w + f2.x * a2hi.x + f2.y * a2hi.y +
                f3.x * a2hi.z + f3.y * a2hi.w;
      d += __shfl_xor(d, 1, 64);
      d += __shfl_xor(d, 2, 64);
      d += __shfl_xor(d, 4, 64);
      float s = sab + __int_as_float(p1.y) + d;
      float ev = (s > 0.f) ? s : 0.01f * s;
      float a = __expf(ev);
      acc[0] = fmaf(a, f0.x, acc[0]); acc[1] = fmaf(a, f0.y, acc[1]);
      acc[2] = fmaf(a, f1.x, acc[2]); acc[3] = fmaf(a, f1.y, acc[3]);
      acc[4] = fmaf(a, f2.x, acc[4]); acc[5] = fmaf(a, f2.y, acc[5]);
      acc[6] = fmaf(a, f3.x, acc[6]); acc[7] = fmaf(a, f3.y, acc[7]);
      if (sub == 0) l += a;
    }
  }
  // reduce across the 8 slot-groups (stride 8)
#pragma unroll
  for (int c = 0; c < 8; ++c) {
    acc[c] += __shfl_xor(acc[c], 8, 64);
    acc[c] += __shfl_xor(acc[c], 16, 64);
    acc[c] += __shfl_xor(acc[c], 32, 64);
  }
  l += __shfl_xor(l, 8, 64);
  l += __shfl_xor(l, 16, 64);
  l += __shfl_xor(l, 32, 64);
  float lt = __shfl(l, 0, 64);
  if (slot == 0) {
    float inv = 1.0f / (lt + 1e-8f);
    float4 o0 = make_float4(acc[0] * inv, acc[1] * inv, acc[2] * inv,
                            acc[3] * inv);
    float4 o1 = make_float4(acc[4] * inv, acc[5] * inv, acc[6] * inv,
                            acc[7] * inv);
    float4* orow = (float4*)out + (size_t)v * 16 + sub * 2;
    orow[0] = o0;
    orow[1] = o1;
  }
}

extern "C" void kernel_launch(void* const* d_in, const int* in_sizes, int n_in,
                              void* d_out, int out_size, void* d_ws, size_t ws_size,
                              hipStream_t stream) {
  const float* h         = (const float*)d_in[0];
  const int*   ei        = (const int*)d_in[1];
  const float* edge_attr = (const float*)d_in[2];
  const float* w_w       = (const float*)d_in[3];
  const float* w_b       = (const float*)d_in[4];
  const float* a_w       = (const float*)d_in[5];
  const float* a_b       = (const float*)d_in[6];
  const int n_nodes = in_sizes[0] / IN_DIM;
  const int nedges  = in_sizes[1] / 2;
  const int nb   = (n_nodes + RPB - 1) / RPB;   // 196
  const int nebl = (nedges + EPB - 1) / EPB;    // 782

  // entA capacity with line padding: nedges + nebl*nb*8 + nb*16
  const size_t entcap = (size_t)nedges + (size_t)nebl * nb * 8 + (size_t)nb * 16;

  // Workspace (~59.3 MB):
  __half* wh       = (__half*)d_ws;                           // n*64 fp16
  int2*  entA      = (int2*)(wh + (size_t)n_nodes * OUT_DIM); // entcap
  int*   cnt       = (int*)(entA + entcap);                   // MAXB
  int*   bbase     = cnt + MAXB;                              // MAXB
  int*   nodeoffs  = bbase + MAXB;                            // n
  int*   nodecnt   = nodeoffs + n_nodes;                      // n
  float* s_row     = (float*)(nodecnt + n_nodes);             // n (lives to k_agg)
  int2*  entB      = (int2*)(s_row + n_nodes);                // entcap
  // Aliases inside entB (all die before k_sortb writes entB):
  int*   blockhist = (int*)entB;                              // nebl*MAXB
  int*   boff      = blockhist + (size_t)nebl * MAXB;         // nebl*MAXB

  k_wh<<<640, 256, 0, stream>>>(h, w_w, w_b, a_w, wh, s_row, n_nodes);
  k_pre<<<nebl, 512, 0, stream>>>(ei, blockhist, nedges);
  k_scanA<<<nb, 512, 0, stream>>>(blockhist, boff, cnt, nebl);
  k_scanB<<<1, 256, 0, stream>>>(cnt, bbase, nb);
  k_fill<<<nebl, 512, 0, stream>>>(ei, edge_attr, a_w, boff, bbase, entA,
                                   nedges, nb);
  k_sortb<<<nb, 512, 0, stream>>>(entA, entB, cnt, bbase, nodeoffs, nodecnt,
                                  n_nodes);
  k_agg<<<(n_nodes + 3) / 4, 256, 0, stream>>>(nodeoffs, nodecnt, entB, wh,
                                               s_row, a_w, a_b,
                                               (float*)d_out, n_nodes);
}